// Round 1
// baseline (435.896 us; speedup 1.0000x reference)
//
#include <hip/hip_runtime.h>

#define N_IN 600000
#define KK 4
#define C_IN 64
#define C_OUT 32
#define N_OUTR (KK*N_IN)
#define BN_EPS 1e-5f

// ws float layout:
// [0,4096)      G (64x64 Gram, final)
// [4096,4160)   s (colsum, final)
// [4160,4192)   scale[32]
// [4192,4224)   bias[32]
// [4224, ...)   per-block partials, 4160 floats each (G 4096 + s 64)
#define WS_G 0
#define WS_S 4096
#define WS_SCALE 4160
#define WS_BIAS 4192
#define WS_PART 4224
#define PART_STRIDE 4160

// Pass A: Gram matrix G = X^T X and column sums s = sum_n x_n.
// Block: 256 threads = 4 waves; each wave processes 8 of the 32 staged rows.
// Each thread owns an 8x8 tile of G in registers (64 accs).
__global__ __launch_bounds__(256) void k_gram(const float* __restrict__ x,
                                              float* __restrict__ ws, int nblk) {
    __shared__ float smem[4160];  // tile staging (2048) then G merge (4096) + s (64)
    const int t = threadIdx.x;
    const int wv = t >> 6;
    const int l = t & 63;
    const int ar = l >> 3;
    const int ac = l & 7;

    float acc[8][8];
#pragma unroll
    for (int i = 0; i < 8; ++i)
#pragma unroll
        for (int j = 0; j < 8; ++j) acc[i][j] = 0.f;
    float cs[8];
#pragma unroll
    for (int j = 0; j < 8; ++j) cs[j] = 0.f;

    const int ntiles = N_IN / 32;  // 18750, exact
    for (int tile = blockIdx.x; tile < ntiles; tile += nblk) {
        const float4* src = (const float4*)(x + (size_t)tile * (32 * 64));
        float4 v0 = src[t * 2 + 0];
        float4 v1 = src[t * 2 + 1];
        __syncthreads();  // previous iteration's readers done
        float4* dst = (float4*)smem;
        dst[t * 2 + 0] = v0;
        dst[t * 2 + 1] = v1;
        cs[0] += v0.x; cs[1] += v0.y; cs[2] += v0.z; cs[3] += v0.w;
        cs[4] += v1.x; cs[5] += v1.y; cs[6] += v1.z; cs[7] += v1.w;
        __syncthreads();
#pragma unroll
        for (int rr = 0; rr < 8; ++rr) {
            const float* row = smem + (wv * 8 + rr) * 64;
            float a[8], b[8];
#pragma unroll
            for (int i = 0; i < 8; ++i) a[i] = row[ar * 8 + i];
#pragma unroll
            for (int j = 0; j < 8; ++j) b[j] = row[ac * 8 + j];
#pragma unroll
            for (int i = 0; i < 8; ++i)
#pragma unroll
                for (int j = 0; j < 8; ++j) acc[i][j] = fmaf(a[i], b[j], acc[i][j]);
        }
    }
    __syncthreads();
    // merge the 4 waves' partial Gs in LDS (sequential phases)
    if (wv == 0) {
#pragma unroll
        for (int i = 0; i < 8; ++i)
#pragma unroll
            for (int j = 0; j < 8; ++j) smem[(ar * 8 + i) * 64 + ac * 8 + j] = acc[i][j];
    }
    __syncthreads();
    for (int w = 1; w < 4; ++w) {
        if (wv == w) {
#pragma unroll
            for (int i = 0; i < 8; ++i)
#pragma unroll
                for (int j = 0; j < 8; ++j) smem[(ar * 8 + i) * 64 + ac * 8 + j] += acc[i][j];
        }
        __syncthreads();
    }
    if (t < 64) smem[4096 + t] = 0.f;
    __syncthreads();
    {
        // thread t's loaded values always map to cols (t&7)*8 + j
        float* sp = smem + 4096 + (t & 7) * 8;
#pragma unroll
        for (int j = 0; j < 8; ++j) atomicAdd(&sp[j], cs[j]);
    }
    __syncthreads();
    float* part = ws + WS_PART + (size_t)blockIdx.x * PART_STRIDE;
    for (int i = t; i < 4160; i += 256) part[i] = smem[i];
}

// Reduce per-block partials -> final G and s.
__global__ void k_reduce(float* __restrict__ ws, int nblk) {
    int j = blockIdx.x * 64 + threadIdx.x;
    if (j >= 4160) return;
    const float* p = ws + WS_PART + j;
    float s = 0.f;
    for (int b = 0; b < nblk; ++b) s += p[(size_t)b * PART_STRIDE];
    ws[j] = s;  // G at [0,4096), s at [4096,4160)
}

// Finalize BN stats: mean_o = (sum_k s.w[k,:,o])/N_OUT,
// E[y^2]_o = (sum_k w[k,:,o]^T G w[k,:,o])/N_OUT; emit scale/bias.
__global__ __launch_bounds__(256) void k_finalize(const float* __restrict__ w,
                                                  const float* __restrict__ gamma,
                                                  const float* __restrict__ beta,
                                                  float* __restrict__ ws) {
    __shared__ float Gs[4096];
    __shared__ float ssum[64];
    __shared__ float red1[256], red2[256];
    const int t = threadIdx.x;
    for (int i = t; i < 4096; i += 256) Gs[i] = ws[i];
    if (t < 64) ssum[t] = ws[WS_S + t];
    __syncthreads();
    const int sub = t >> 7;       // split the i-range in half across 2 thread groups
    const int k = (t >> 5) & 3;
    const int o = t & 31;
    float wc[64];
#pragma unroll
    for (int i = 0; i < 64; ++i) wc[i] = w[(k * 64 + i) * 32 + o];
    float m1 = 0.f, m2 = 0.f;
    for (int ii = 0; ii < 32; ++ii) {
        int i = sub * 32 + ii;
        m1 = fmaf(ssum[i], wc[i], m1);
        float ti = 0.f;
#pragma unroll
        for (int j = 0; j < 64; ++j) ti = fmaf(Gs[i * 64 + j], wc[j], ti);
        m2 = fmaf(wc[i], ti, m2);
    }
    red1[t] = m1;
    red2[t] = m2;
    __syncthreads();
    if (t < 32) {
        float s1 = 0.f, s2 = 0.f;
#pragma unroll
        for (int q = 0; q < 8; ++q) {
            int idx = (q & 3) * 32 + (q >> 2) * 128 + t;
            s1 += red1[idx];
            s2 += red2[idx];
        }
        float inv = 1.f / (float)N_OUTR;
        float mean = s1 * inv;
        float var = s2 * inv - mean * mean;
        float rstd = rsqrtf(var + BN_EPS);
        float sc = gamma[t] * rstd;
        ws[WS_SCALE + t] = sc;
        ws[WS_BIAS + t] = beta[t] - mean * sc;
    }
}

// Main pass: lane-per-row GEMM (w via wave-uniform scalar loads),
// fused normalize + ReLU + permutation scatter of 128B rows.
__global__ __launch_bounds__(256, 3) void k_main(const float* __restrict__ x,
                                                 const float* __restrict__ w,
                                                 const int* __restrict__ oidx,
                                                 const float* __restrict__ ws,
                                                 float* __restrict__ out) {
    const int r = blockIdx.x * 256 + threadIdx.x;
    const bool valid = (r < N_IN);
    float xr[64];
    if (valid) {
        const float4* xp = (const float4*)(x + (size_t)r * 64);
#pragma unroll
        for (int i = 0; i < 16; ++i) {
            float4 v = xp[i];
            xr[4 * i + 0] = v.x; xr[4 * i + 1] = v.y;
            xr[4 * i + 2] = v.z; xr[4 * i + 3] = v.w;
        }
    } else {
#pragma unroll
        for (int i = 0; i < 64; ++i) xr[i] = 0.f;
    }
#pragma unroll 1
    for (int k = 0; k < 4; ++k) {
        const float* wk = w + k * (C_IN * C_OUT);
        float acc[32];
#pragma unroll
        for (int o = 0; o < 32; ++o) acc[o] = 0.f;
#pragma unroll
        for (int i = 0; i < 64; ++i) {
            const float xv = xr[i];
#pragma unroll
            for (int o = 0; o < 32; ++o) acc[o] = fmaf(xv, wk[i * 32 + o], acc[o]);
        }
        if (valid) {
            const int orow = oidx[(size_t)k * N_IN + r];
            float4* op = (float4*)(out + (size_t)orow * 32);
#pragma unroll
            for (int q = 0; q < 8; ++q) {
                float4 v;
                v.x = fmaxf(0.f, fmaf(acc[4 * q + 0], ws[WS_SCALE + 4 * q + 0], ws[WS_BIAS + 4 * q + 0]));
                v.y = fmaxf(0.f, fmaf(acc[4 * q + 1], ws[WS_SCALE + 4 * q + 1], ws[WS_BIAS + 4 * q + 1]));
                v.z = fmaxf(0.f, fmaf(acc[4 * q + 2], ws[WS_SCALE + 4 * q + 2], ws[WS_BIAS + 4 * q + 2]));
                v.w = fmaxf(0.f, fmaf(acc[4 * q + 3], ws[WS_SCALE + 4 * q + 3], ws[WS_BIAS + 4 * q + 3]));
                op[q] = v;
            }
        }
    }
}

extern "C" void kernel_launch(void* const* d_in, const int* in_sizes, int n_in,
                              void* d_out, int out_size, void* d_ws, size_t ws_size,
                              hipStream_t stream) {
    const float* x = (const float*)d_in[0];
    const float* w = (const float*)d_in[1];
    const float* gamma = (const float*)d_in[2];
    const float* beta = (const float*)d_in[3];
    const int* oidx = (const int*)d_in[4];
    float* out = (float*)d_out;
    float* ws = (float*)d_ws;

    int nba = 512;  // 2 blocks/CU for the Gram pass
    size_t need = ((size_t)WS_PART + (size_t)nba * PART_STRIDE) * sizeof(float);
    if (need > ws_size) {
        size_t fit = (ws_size / sizeof(float) - WS_PART) / PART_STRIDE;
        nba = (int)(fit < 1 ? 1 : fit);
        if (nba > 512) nba = 512;
    }

    hipLaunchKernelGGL(k_gram, dim3(nba), dim3(256), 0, stream, x, ws, nba);
    hipLaunchKernelGGL(k_reduce, dim3(65), dim3(64), 0, stream, ws, nba);
    hipLaunchKernelGGL(k_finalize, dim3(1), dim3(256), 0, stream, w, gamma, beta, ws);
    hipLaunchKernelGGL(k_main, dim3((N_IN + 255) / 256), dim3(256), 0, stream,
                       x, w, oidx, ws, out);
}

// Round 2
// 290.934 us; speedup vs baseline: 1.4983x; 1.4983x over previous
//
#include <hip/hip_runtime.h>

#define N_IN 600000
#define KK 4
#define C_IN 64
#define C_OUT 32
#define NTOT (KK*N_IN)
#define BN_EPS 1e-5f

typedef __attribute__((ext_vector_type(8))) short short8b;   // 8 bf16 (4 VGPRs)
typedef __attribute__((ext_vector_type(4))) float f32x4;     // MFMA C/D

// ws float layout:
// [0,4096)      G (64x64 Gram, final)
// [4096,4160)   s (colsum, final)
// [4160,4192)   scale[32]
// [4192,4224)   bias[32]
// [4224,8320)   W bf16 fragments (1024 uint4 = 16KB)
// [8320,...)    per-block gram partials, 4160 floats each
#define WS_G 0
#define WS_S 4096
#define WS_SCALE 4160
#define WS_BIAS 4192
#define WS_WFRAG 4224
#define WS_PART 8320
#define PART_STRIDE 4160

__device__ __forceinline__ unsigned short f2bf(float f) {
    unsigned int u = __float_as_uint(f);
    u += 0x7fffu + ((u >> 16) & 1u);   // RNE
    return (unsigned short)(u >> 16);
}

union FragU { uint4 u; short8b s; };

// ---------------- Pass A: Gram G = X^T X, colsums s -------------------------
__global__ __launch_bounds__(256) void k_gram(const float* __restrict__ x,
                                              float* __restrict__ ws) {
    __shared__ float sm[4160];  // 64x64 stage (4096) reused for merge; +64 for s
    const int t = threadIdx.x;
    const int wv = t >> 6, l = t & 63;
    const int ar = l >> 3, ac = l & 7;

    float acc[8][8];
#pragma unroll
    for (int i = 0; i < 8; ++i)
#pragma unroll
        for (int j = 0; j < 8; ++j) acc[i][j] = 0.f;
    float cs[4] = {0.f, 0.f, 0.f, 0.f};

    const int ntiles = N_IN / 64;  // 9375
    for (int tile = blockIdx.x; tile < ntiles; tile += gridDim.x) {
        const float4* src = (const float4*)(x + (size_t)tile * 4096);
        float4 v[4];
#pragma unroll
        for (int i = 0; i < 4; ++i) v[i] = src[i * 256 + t];
        __syncthreads();  // previous tile's readers done
        float4* dst = (float4*)sm;
#pragma unroll
        for (int i = 0; i < 4; ++i) {
            dst[i * 256 + t] = v[i];
            cs[0] += v[i].x; cs[1] += v[i].y; cs[2] += v[i].z; cs[3] += v[i].w;
        }
        __syncthreads();
#pragma unroll 4
        for (int rr = 0; rr < 16; ++rr) {
            const float* row = sm + (wv * 16 + rr) * 64;
            float4 a0 = *(const float4*)(row + ar * 8);
            float4 a1 = *(const float4*)(row + ar * 8 + 4);
            float4 b0 = *(const float4*)(row + ac * 8);
            float4 b1 = *(const float4*)(row + ac * 8 + 4);
            float a[8] = {a0.x, a0.y, a0.z, a0.w, a1.x, a1.y, a1.z, a1.w};
            float b[8] = {b0.x, b0.y, b0.z, b0.w, b1.x, b1.y, b1.z, b1.w};
#pragma unroll
            for (int i = 0; i < 8; ++i)
#pragma unroll
                for (int j = 0; j < 8; ++j) acc[i][j] = fmaf(a[i], b[j], acc[i][j]);
        }
    }
    // colsum: deterministic butterfly over lanes sharing (l&15)
#pragma unroll
    for (int j = 0; j < 4; ++j) {
        cs[j] += __shfl_xor(cs[j], 16, 64);
        cs[j] += __shfl_xor(cs[j], 32, 64);
    }
    __syncthreads();
    // merge 4 waves' G partials in LDS, sequential (deterministic)
    if (wv == 0) {
#pragma unroll
        for (int i = 0; i < 8; ++i)
#pragma unroll
            for (int j = 0; j < 8; ++j) sm[(ar * 8 + i) * 64 + ac * 8 + j] = acc[i][j];
    }
    __syncthreads();
    for (int w = 1; w < 4; ++w) {
        if (wv == w) {
#pragma unroll
            for (int i = 0; i < 8; ++i)
#pragma unroll
                for (int j = 0; j < 8; ++j) sm[(ar * 8 + i) * 64 + ac * 8 + j] += acc[i][j];
        }
        __syncthreads();
    }
    if (wv == 0 && l < 16) {
#pragma unroll
        for (int j = 0; j < 4; ++j) sm[4096 + l * 4 + j] = cs[j];
    }
    __syncthreads();
    for (int w = 1; w < 4; ++w) {
        if (wv == w && l < 16) {
#pragma unroll
            for (int j = 0; j < 4; ++j) sm[4096 + l * 4 + j] += cs[j];
        }
        __syncthreads();
    }
    float* part = ws + WS_PART + (size_t)blockIdx.x * PART_STRIDE;
    for (int i = t; i < 4160; i += 256) part[i] = sm[i];
}

// ---------------- Reduce partials: one wave per output element --------------
__global__ __launch_bounds__(256) void k_reduce(float* __restrict__ ws, int nba) {
    const int g = blockIdx.x * 4 + (threadIdx.x >> 6);  // 0..4159
    const int lane = threadIdx.x & 63;
    const float* p = ws + WS_PART + g;
    float s = 0.f;
    for (int b = lane; b < nba; b += 64) s += p[(size_t)b * PART_STRIDE];
#pragma unroll
    for (int m = 1; m < 64; m <<= 1) s += __shfl_xor(s, m, 64);
    if (lane == 0) ws[g] = s;
}

// ---------------- Finalize BN stats -> scale/bias ---------------------------
__global__ __launch_bounds__(256) void k_finalize(const float* __restrict__ w,
                                                  const float* __restrict__ gamma,
                                                  const float* __restrict__ beta,
                                                  float* __restrict__ ws) {
    __shared__ float Gs[4096];
    __shared__ float ssum[64];
    __shared__ float red1[256], red2[256];
    const int t = threadIdx.x;
    for (int i = t; i < 4096; i += 256) Gs[i] = ws[i];
    if (t < 64) ssum[t] = ws[WS_S + t];
    __syncthreads();
    const int sub = t >> 7;
    const int k = (t >> 5) & 3;
    const int o = t & 31;
    float wc[64];
#pragma unroll
    for (int i = 0; i < 64; ++i) wc[i] = w[(k * 64 + i) * 32 + o];
    float m1 = 0.f, m2 = 0.f;
    for (int ii = 0; ii < 32; ++ii) {
        int i = sub * 32 + ii;
        m1 = fmaf(ssum[i], wc[i], m1);
        float ti = 0.f;
#pragma unroll
        for (int j = 0; j < 64; ++j) ti = fmaf(Gs[i * 64 + j], wc[j], ti);
        m2 = fmaf(wc[i], ti, m2);
    }
    red1[t] = m1;
    red2[t] = m2;
    __syncthreads();
    if (t < 32) {
        float s1 = 0.f, s2 = 0.f;
#pragma unroll
        for (int q = 0; q < 8; ++q) {
            int idx = (q & 3) * 32 + (q >> 2) * 128 + t;
            s1 += red1[idx];
            s2 += red2[idx];
        }
        float inv = 1.f / (float)NTOT;
        float mean = s1 * inv;
        float var = s2 * inv - mean * mean;
        float rstd = rsqrtf(var + BN_EPS);
        float sc = gamma[t] * rstd;
        ws[WS_SCALE + t] = sc;
        ws[WS_BIAS + t] = beta[t] - mean * sc;
    }
}

// ---------------- Pack W into MFMA B-fragment layout (bf16) -----------------
// frag f = c*2+s (c=col-tile 0..7, s=kstep 0..1); lane l holds
// B[s*32+(l>>4)*8+j][c*16+(l&15)], j=0..7, packed 2 bf16 per uint.
__global__ __launch_bounds__(256) void k_prepw(const float* __restrict__ w,
                                               float* __restrict__ ws) {
    const int t = blockIdx.x * 256 + threadIdx.x;  // 0..1023
    const int l = t & 63;
    const int s = (t >> 6) & 1;
    const int c = t >> 7;
    const int col = c * 16 + (l & 15);
    const int kk = col >> 5, o = col & 31;
    unsigned int pk[4];
#pragma unroll
    for (int jj = 0; jj < 4; ++jj) {
        const int k0 = s * 32 + ((l >> 4) << 3) + jj * 2;
        unsigned int b0 = f2bf(w[(kk * 64 + k0) * 32 + o]);
        unsigned int b1 = f2bf(w[(kk * 64 + k0 + 1) * 32 + o]);
        pk[jj] = b0 | (b1 << 16);
    }
    uint4* dst = (uint4*)(ws + WS_WFRAG);
    dst[t] = make_uint4(pk[0], pk[1], pk[2], pk[3]);
}

// ---------------- Main: MFMA GEMM + BN + ReLU + scatter ---------------------
__global__ __launch_bounds__(256, 3) void k_main(const float* __restrict__ x,
                                                 const int* __restrict__ oidx,
                                                 const float* __restrict__ ws,
                                                 float* __restrict__ out) {
    __shared__ float lds[4][64 * 36];  // per-wave 64 rows x 32 fl (+4 pad), XOR-swizzled
    const int t = threadIdx.x, wv = t >> 6, l = t & 63;
    const int il = l & 15, g = l >> 4;

    // all of W as 16 B-fragments, resident in VGPRs
    short8b bf[16];
    const uint4* wf = (const uint4*)(ws + WS_WFRAG);
#pragma unroll
    for (int f = 0; f < 16; ++f) {
        FragU fu;
        fu.u = wf[f * 64 + l];
        bf[f] = fu.s;
    }
    const float sc0 = ws[WS_SCALE + il], sc1 = ws[WS_SCALE + 16 + il];
    const float bs0 = ws[WS_BIAS + il], bs1 = ws[WS_BIAS + 16 + il];

    const int wgid = blockIdx.x * 4 + wv;
    const int nw = gridDim.x * 4;
    const int ntiles = N_IN / 16;  // 37500

    for (int tile = wgid; tile < ntiles; tile += nw) {
        const int rowbase = tile * 16;
        f32x4 acc[8];
#pragma unroll
        for (int c = 0; c < 8; ++c) acc[c] = (f32x4){0.f, 0.f, 0.f, 0.f};

#pragma unroll
        for (int s = 0; s < 2; ++s) {
            // A-frag: row = l&15, k = s*32 + (l>>4)*8 + j
            const float* ap = x + (size_t)(rowbase + il) * 64 + s * 32 + g * 8;
            float4 a0 = *(const float4*)ap;
            float4 a1 = *(const float4*)(ap + 4);
            FragU af;
            af.u.x = (unsigned)f2bf(a0.x) | ((unsigned)f2bf(a0.y) << 16);
            af.u.y = (unsigned)f2bf(a0.z) | ((unsigned)f2bf(a0.w) << 16);
            af.u.z = (unsigned)f2bf(a1.x) | ((unsigned)f2bf(a1.y) << 16);
            af.u.w = (unsigned)f2bf(a1.z) | ((unsigned)f2bf(a1.w) << 16);
#pragma unroll
            for (int c = 0; c < 8; ++c)
                acc[c] = __builtin_amdgcn_mfma_f32_16x16x32_bf16(af.s, bf[c * 2 + s], acc[c], 0, 0, 0);
        }

        // BN+ReLU in-reg, then XOR-swizzled LDS transpose (wave-private region)
        float* myl = lds[wv];
#pragma unroll
        for (int c = 0; c < 8; ++c) {
            const float sc = (c & 1) ? sc1 : sc0;
            const float bs = (c & 1) ? bs1 : bs0;
            const int koff = (c >> 1) * 16;
            const int off = (c & 1) * 16 + il;
            const int mo = off >> 2, o3 = off & 3;
#pragma unroll
            for (int q = 0; q < 4; ++q) {
                const int orow = koff + g * 4 + q;  // local out-row = k*16 + r
                const float v = fmaxf(0.f, fmaf(acc[c][q], sc, bs));
                myl[orow * 36 + ((mo ^ (orow >> 3)) << 2) + o3] = v;
            }
        }
        // lane l owns local out-row l: k = l>>4, r = l&15
        const int orow = oidx[g * N_IN + rowbase + il];
        const float* rp = myl + l * 36;
        float4* op = (float4*)(out + (size_t)orow * 32);
#pragma unroll
        for (int m = 0; m < 8; ++m) {
            op[m] = *(const float4*)(rp + ((m ^ (l >> 3)) << 2));
        }
    }
}

extern "C" void kernel_launch(void* const* d_in, const int* in_sizes, int n_in,
                              void* d_out, int out_size, void* d_ws, size_t ws_size,
                              hipStream_t stream) {
    const float* x = (const float*)d_in[0];
    const float* w = (const float*)d_in[1];
    const float* gamma = (const float*)d_in[2];
    const float* beta = (const float*)d_in[3];
    const int* oidx = (const int*)d_in[4];
    float* out = (float*)d_out;
    float* ws = (float*)d_ws;

    int nba = 512;
    size_t need = ((size_t)WS_PART + (size_t)nba * PART_STRIDE) * sizeof(float);
    if (need > ws_size) {
        size_t fit = (ws_size / sizeof(float) - WS_PART) / PART_STRIDE;
        nba = (int)(fit < 1 ? 1 : fit);
        if (nba > 512) nba = 512;
    }

    hipLaunchKernelGGL(k_prepw, dim3(4), dim3(256), 0, stream, w, ws);
    hipLaunchKernelGGL(k_gram, dim3(nba), dim3(256), 0, stream, x, ws);
    hipLaunchKernelGGL(k_reduce, dim3(1040), dim3(256), 0, stream, ws, nba);
    hipLaunchKernelGGL(k_finalize, dim3(1), dim3(256), 0, stream, w, gamma, beta, ws);
    hipLaunchKernelGGL(k_main, dim3(1536), dim3(256), 0, stream, x, oidx, ws, out);
}